// Round 1
// baseline (58567.371 us; speedup 1.0000x reference)
//
#include <hip/hip_runtime.h>

#define T_LEN 8192
#define EDIM 512
#define HDIM 512
#define H4 2048
#define NCHUNK 16   // blocks per direction
// each block owns 32 h-elements (512/16)

typedef __attribute__((ext_vector_type(8))) short bf16x8;
typedef __attribute__((ext_vector_type(4))) float f32x4;

__device__ __forceinline__ unsigned short f2bf(float x) {
  unsigned u = __float_as_uint(x);
  u += 0x7FFFu + ((u >> 16) & 1u);   // round-to-nearest-even
  return (unsigned short)(u >> 16);
}

// ---------------- prep: embedding gather + cast to bf16 ----------------
__global__ __launch_bounds__(256) void prep_emb(const int* __restrict__ idx,
                                                const float* __restrict__ table,
                                                unsigned short* __restrict__ emb) {
  int t = blockIdx.x;
  int k = threadIdx.x * 2;
  float2 v = *(const float2*)(table + (size_t)idx[t] * EDIM + k);
  ushort2 o;
  o.x = f2bf(v.x);
  o.y = f2bf(v.y);
  *(ushort2*)(emb + (size_t)t * EDIM + k) = o;
}

// ---------------- prep: Wih concat cast + bias sums ----------------
__global__ __launch_bounds__(256) void prep_w(const float* __restrict__ Wf,
                                              const float* __restrict__ Wb,
                                              const float* __restrict__ bif,
                                              const float* __restrict__ bhf,
                                              const float* __restrict__ bib,
                                              const float* __restrict__ bhb,
                                              unsigned short* __restrict__ WT,
                                              float* __restrict__ bias) {
  size_t gid = (size_t)blockIdx.x * 256 + threadIdx.x;  // 0 .. 4096*512
  float v = (gid < (size_t)H4 * EDIM) ? Wf[gid] : Wb[gid - (size_t)H4 * EDIM];
  WT[gid] = f2bf(v);
  if (gid < 2 * H4) {
    bias[gid] = (gid < H4) ? (bif[gid] + bhf[gid]) : (bib[gid - H4] + bhb[gid - H4]);
  }
}

// ---------------- x_proj GEMM: [8192,512]bf16 x [512,4096]bf16 -> f32 + bias ----------------
// A row-major [M,K], BT row-major [N,K]; 128x128 tile, BK=32, 4 waves.
__global__ __launch_bounds__(256) void gemm_xp(const unsigned short* __restrict__ A,
                                               const unsigned short* __restrict__ BT,
                                               const float* __restrict__ bias,
                                               float* __restrict__ C) {
  __shared__ unsigned short As[128 * 32];
  __shared__ unsigned short Bs[128 * 32];
  const int GN = 2 * H4;  // 4096
  const int GK = EDIM;    // 512
  int bm = blockIdx.x >> 5;   // 0..63
  int bn = blockIdx.x & 31;   // 0..31
  int tid = threadIdx.x;
  int wave = tid >> 6, lane = tid & 63;
  int wr = (wave >> 1) * 64, wc = (wave & 1) * 64;
  int lrow = lane & 15, lk = (lane >> 4) * 8;
  f32x4 acc[4][4] = {};
  int sr = tid >> 1;          // staging row 0..127
  int sc = (tid & 1) * 16;    // staging col (elems): 0 or 16
  const size_t arow = (size_t)(bm * 128 + sr) * GK;
  const size_t brow = (size_t)(bn * 128 + sr) * GK;
  for (int k0 = 0; k0 < GK; k0 += 32) {
    __syncthreads();
    const uint4* sa = (const uint4*)(A + arow + k0 + sc);
    uint4 a0 = sa[0], a1 = sa[1];
    const uint4* sb = (const uint4*)(BT + brow + k0 + sc);
    uint4 b0 = sb[0], b1 = sb[1];
    uint4* da = (uint4*)&As[sr * 32 + sc]; da[0] = a0; da[1] = a1;
    uint4* db = (uint4*)&Bs[sr * 32 + sc]; db[0] = b0; db[1] = b1;
    __syncthreads();
    bf16x8 af[4], bfr[4];
#pragma unroll
    for (int m = 0; m < 4; ++m) af[m] = *(const bf16x8*)&As[(wr + m * 16 + lrow) * 32 + lk];
#pragma unroll
    for (int n = 0; n < 4; ++n) bfr[n] = *(const bf16x8*)&Bs[(wc + n * 16 + lrow) * 32 + lk];
#pragma unroll
    for (int m = 0; m < 4; ++m)
#pragma unroll
      for (int n = 0; n < 4; ++n)
        acc[m][n] = __builtin_amdgcn_mfma_f32_16x16x32_bf16(af[m], bfr[n], acc[m][n], 0, 0, 0);
  }
  int crow = bm * 128 + wr + (lane >> 4) * 4;
  int ccol0 = bn * 128 + wc + lrow;
#pragma unroll
  for (int m = 0; m < 4; ++m)
#pragma unroll
    for (int n = 0; n < 4; ++n) {
      int col = ccol0 + n * 16;
      float bv = bias[col];
#pragma unroll
      for (int r = 0; r < 4; ++r)
        C[(size_t)(crow + m * 16 + r) * GN + col] = acc[m][n][r] + bv;
    }
}

// ---------------- recurrence: 32 persistent blocks (16/direction), weights in VGPRs ----------------
// Block b: dir = b>>4, chunk m = b&15 -> owns h elements [32m, 32m+32).
// Thread t: row_local = t>>2 (0..127), kseg = t&3 (128-elem K segment).
// Per step: 128 f32 FMAs/thread, 4-lane shfl reduce, gates -> LDS, 32 threads do activations,
// h broadcast via global memory + per-(step,chunk) release/acquire flags.
__global__ __launch_bounds__(512, 2) void lstm_recur(const float* __restrict__ Whh_f,
                                                     const float* __restrict__ Whh_b,
                                                     const float* __restrict__ xp,
                                                     float* __restrict__ h_hist,
                                                     unsigned* __restrict__ flags) {
  int b = blockIdx.x;
  int dir = b >> 4;
  int m = b & 15;
  int tid = threadIdx.x;
  const float* Whh = dir ? Whh_b : Whh_f;
  int row_local = tid >> 2;
  int kseg = tid & 3;
  int R = ((row_local >> 5) << 9) + (m << 5) + (row_local & 31);  // gate*512 + m*32 + jj
  float w[128];
  {
    const float4* wsrc = (const float4*)(Whh + (size_t)R * HDIM + kseg * 128);
#pragma unroll
    for (int u = 0; u < 32; ++u) {
      float4 v = wsrc[u];
      w[4 * u] = v.x; w[4 * u + 1] = v.y; w[4 * u + 2] = v.z; w[4 * u + 3] = v.w;
    }
  }
  // padded h staging: value v stored at (v>>7)*132 + (v&127)  -> kseg bases on distinct banks
  __shared__ float h_lds[2][544];
  __shared__ float gates_lds[128];
  float c = 0.f;
  unsigned* myflags = flags + (size_t)dir * T_LEN * NCHUNK;
  float* h_dir = h_hist + (size_t)dir * T_LEN * HDIM;
  const float* xp_dir = xp + dir * H4;
  int pollpos = ((tid >> 7) * 132) + (tid & 127);
  int hbase_off = kseg * 132;

  for (int s = 0; s < T_LEN; ++s) {
    int pos = dir ? (T_LEN - 1 - s) : s;
    // prefetch x_proj for this step early (latency hides under poll + matvec)
    float xi = 0.f, xf_ = 0.f, xg = 0.f, xo = 0.f;
    if (tid < 32) {
      const float* xr = xp_dir + (size_t)pos * (2 * H4) + (m << 5) + tid;
      xi = xr[0]; xf_ = xr[512]; xg = xr[1024]; xo = xr[1536];
    }
    int buf = s & 1;
    if (s == 0) {
      h_lds[0][pollpos] = 0.f;
    } else {
      int prevpos = dir ? (pos + 1) : (pos - 1);
      const unsigned* fp = myflags + (size_t)(s - 1) * NCHUNK + (tid >> 5);
      while (__hip_atomic_load(fp, __ATOMIC_ACQUIRE, __HIP_MEMORY_SCOPE_AGENT) != (unsigned)s) {}
      float hv = __hip_atomic_load(h_dir + (size_t)prevpos * HDIM + tid,
                                   __ATOMIC_RELAXED, __HIP_MEMORY_SCOPE_AGENT);
      h_lds[buf][pollpos] = hv;
    }
    __syncthreads();
    // matvec partial: 128 FMAs over this thread's K segment
    float part = 0.f;
    const float* hb = &h_lds[buf][hbase_off];
#pragma unroll
    for (int u = 0; u < 32; ++u) {
      float4 h4 = *(const float4*)(hb + u * 4);
      part = fmaf(w[4 * u], h4.x, part);
      part = fmaf(w[4 * u + 1], h4.y, part);
      part = fmaf(w[4 * u + 2], h4.z, part);
      part = fmaf(w[4 * u + 3], h4.w, part);
    }
    part += __shfl_xor(part, 1);
    part += __shfl_xor(part, 2);
    if (kseg == 0) gates_lds[row_local] = part;
    __syncthreads();
    if (tid < 32) {
      float gi = gates_lds[tid] + xi;
      float gf = gates_lds[32 + tid] + xf_;
      float gg = gates_lds[64 + tid] + xg;
      float go = gates_lds[96 + tid] + xo;
      float iv = 1.f / (1.f + __expf(-gi));
      float fv = 1.f / (1.f + __expf(-gf));
      float gv = 1.f - 2.f / (1.f + __expf(2.f * gg));
      float ov = 1.f / (1.f + __expf(-go));
      c = fmaf(fv, c, iv * gv);
      float hv = ov * (1.f - 2.f / (1.f + __expf(2.f * c)));
      __hip_atomic_store(h_dir + (size_t)pos * HDIM + (m << 5) + tid, hv,
                         __ATOMIC_RELAXED, __HIP_MEMORY_SCOPE_AGENT);
    }
    if (tid == 0) {
      // release-store waits the wave's outstanding h-stores (vmcnt) before publishing
      __hip_atomic_store(myflags + (size_t)s * NCHUNK + m, (unsigned)(s + 1),
                         __ATOMIC_RELEASE, __HIP_MEMORY_SCOPE_AGENT);
    }
  }
}

// ---------------- head: [h_f ; h_b] @ W_out.T + b_out, then log_softmax ----------------
__global__ __launch_bounds__(256) void head_ls(const float* __restrict__ h_hist,
                                               const float* __restrict__ W_out,
                                               const float* __restrict__ b_out,
                                               float* __restrict__ out) {
  int gw = (int)((blockIdx.x * 256 + threadIdx.x) >> 6);  // one wave per timestep
  int lane = threadIdx.x & 63;
  if (gw >= T_LEN) return;
  const float* hf = h_hist + (size_t)gw * HDIM;
  const float* hb = h_hist + (size_t)(T_LEN + gw) * HDIM;
  float p0 = 0.f, p1 = 0.f;
#pragma unroll
  for (int k = 0; k < 8; ++k) {
    int kk = lane + k * 64;
    float vf = hf[kk];
    float vb = hb[kk];
    p0 += vf * W_out[kk] + vb * W_out[512 + kk];
    p1 += vf * W_out[1024 + kk] + vb * W_out[1536 + kk];
  }
#pragma unroll
  for (int off = 32; off > 0; off >>= 1) {
    p0 += __shfl_down(p0, off);
    p1 += __shfl_down(p1, off);
  }
  if (lane == 0) {
    float z0 = p0 + b_out[0];
    float z1 = p1 + b_out[1];
    float mx = fmaxf(z0, z1);
    float lse = mx + logf(expf(z0 - mx) + expf(z1 - mx));
    out[(size_t)gw * 2] = z0 - lse;
    out[(size_t)gw * 2 + 1] = z1 - lse;
  }
}

extern "C" void kernel_launch(void* const* d_in, const int* in_sizes, int n_in,
                              void* d_out, int out_size, void* d_ws, size_t ws_size,
                              hipStream_t stream) {
  const int* idx = (const int*)d_in[0];
  const float* table = (const float*)d_in[1];
  const float* Wih_f = (const float*)d_in[2];
  const float* Whh_f = (const float*)d_in[3];
  const float* bih_f = (const float*)d_in[4];
  const float* bhh_f = (const float*)d_in[5];
  const float* Wih_b = (const float*)d_in[6];
  const float* Whh_b = (const float*)d_in[7];
  const float* bih_b = (const float*)d_in[8];
  const float* bhh_b = (const float*)d_in[9];
  const float* W_out = (const float*)d_in[10];
  const float* b_out = (const float*)d_in[11];
  float* out = (float*)d_out;
  char* ws = (char*)d_ws;

  // workspace layout (bytes)
  float* xp = (float*)(ws + 0);                               // [8192][4096] f32 = 128 MiB
  float* h_hist = (float*)(ws + 134217728ULL);                // [2][8192][512] f32 = 32 MiB
  unsigned* flags = (unsigned*)(ws + 167772160ULL);           // [2][8192][16] u32 = 2 MiB
  unsigned short* emb = (unsigned short*)(ws + 169869312ULL); // [8192][512] bf16 = 8 MiB
  unsigned short* wih = (unsigned short*)(ws + 178257920ULL); // [4096][512] bf16 = 4 MiB
  float* bias = (float*)(ws + 182452224ULL);                  // [4096] f32

  hipLaunchKernelGGL(prep_emb, dim3(T_LEN), dim3(256), 0, stream, idx, table, emb);
  hipLaunchKernelGGL(prep_w, dim3(8192), dim3(256), 0, stream,
                     Wih_f, Wih_b, bih_f, bhh_f, bih_b, bhh_b, wih, bias);
  hipLaunchKernelGGL(gemm_xp, dim3(2048), dim3(256), 0, stream, emb, wih, bias, xp);
  hipLaunchKernelGGL(lstm_recur, dim3(32), dim3(512), 0, stream, Whh_f, Whh_b, xp, h_hist, flags);
  hipLaunchKernelGGL(head_ls, dim3(2048), dim3(256), 0, stream, h_hist, W_out, b_out, out);
}

// Round 2
// 19998.366 us; speedup vs baseline: 2.9286x; 2.9286x over previous
//
#include <hip/hip_runtime.h>

#define T_LEN 8192
#define EDIM 512
#define HDIM 512
#define H4 2048
#define NCHUNK 16   // blocks per direction
// each block owns 32 h-elements (512/16)

typedef __attribute__((ext_vector_type(8))) short bf16x8;
typedef __attribute__((ext_vector_type(4))) float f32x4;

__device__ __forceinline__ unsigned short f2bf(float x) {
  unsigned u = __float_as_uint(x);
  u += 0x7FFFu + ((u >> 16) & 1u);   // round-to-nearest-even
  return (unsigned short)(u >> 16);
}

// ---------------- prep: embedding gather + cast to bf16 ----------------
__global__ __launch_bounds__(256) void prep_emb(const int* __restrict__ idx,
                                                const float* __restrict__ table,
                                                unsigned short* __restrict__ emb) {
  int t = blockIdx.x;
  int k = threadIdx.x * 2;
  float2 v = *(const float2*)(table + (size_t)idx[t] * EDIM + k);
  ushort2 o;
  o.x = f2bf(v.x);
  o.y = f2bf(v.y);
  *(ushort2*)(emb + (size_t)t * EDIM + k) = o;
}

// ---------------- prep: Wih concat cast + bias sums ----------------
__global__ __launch_bounds__(256) void prep_w(const float* __restrict__ Wf,
                                              const float* __restrict__ Wb,
                                              const float* __restrict__ bif,
                                              const float* __restrict__ bhf,
                                              const float* __restrict__ bib,
                                              const float* __restrict__ bhb,
                                              unsigned short* __restrict__ WT,
                                              float* __restrict__ bias) {
  size_t gid = (size_t)blockIdx.x * 256 + threadIdx.x;  // 0 .. 4096*512
  float v = (gid < (size_t)H4 * EDIM) ? Wf[gid] : Wb[gid - (size_t)H4 * EDIM];
  WT[gid] = f2bf(v);
  if (gid < 2 * H4) {
    bias[gid] = (gid < H4) ? (bif[gid] + bhf[gid]) : (bib[gid - H4] + bhb[gid - H4]);
  }
}

// ---------------- x_proj GEMM: [8192,512]bf16 x [512,4096]bf16 -> f32 + bias ----------------
// A row-major [M,K], BT row-major [N,K]; 128x128 tile, BK=32, 4 waves.
__global__ __launch_bounds__(256) void gemm_xp(const unsigned short* __restrict__ A,
                                               const unsigned short* __restrict__ BT,
                                               const float* __restrict__ bias,
                                               float* __restrict__ C) {
  __shared__ unsigned short As[128 * 32];
  __shared__ unsigned short Bs[128 * 32];
  const int GN = 2 * H4;  // 4096
  const int GK = EDIM;    // 512
  int bm = blockIdx.x >> 5;   // 0..63
  int bn = blockIdx.x & 31;   // 0..31
  int tid = threadIdx.x;
  int wave = tid >> 6, lane = tid & 63;
  int wr = (wave >> 1) * 64, wc = (wave & 1) * 64;
  int lrow = lane & 15, lk = (lane >> 4) * 8;
  f32x4 acc[4][4] = {};
  int sr = tid >> 1;          // staging row 0..127
  int sc = (tid & 1) * 16;    // staging col (elems): 0 or 16
  const size_t arow = (size_t)(bm * 128 + sr) * GK;
  const size_t brow = (size_t)(bn * 128 + sr) * GK;
  for (int k0 = 0; k0 < GK; k0 += 32) {
    __syncthreads();
    const uint4* sa = (const uint4*)(A + arow + k0 + sc);
    uint4 a0 = sa[0], a1 = sa[1];
    const uint4* sb = (const uint4*)(BT + brow + k0 + sc);
    uint4 b0 = sb[0], b1 = sb[1];
    uint4* da = (uint4*)&As[sr * 32 + sc]; da[0] = a0; da[1] = a1;
    uint4* db = (uint4*)&Bs[sr * 32 + sc]; db[0] = b0; db[1] = b1;
    __syncthreads();
    bf16x8 af[4], bfr[4];
#pragma unroll
    for (int m = 0; m < 4; ++m) af[m] = *(const bf16x8*)&As[(wr + m * 16 + lrow) * 32 + lk];
#pragma unroll
    for (int n = 0; n < 4; ++n) bfr[n] = *(const bf16x8*)&Bs[(wc + n * 16 + lrow) * 32 + lk];
#pragma unroll
    for (int m = 0; m < 4; ++m)
#pragma unroll
      for (int n = 0; n < 4; ++n)
        acc[m][n] = __builtin_amdgcn_mfma_f32_16x16x32_bf16(af[m], bfr[n], acc[m][n], 0, 0, 0);
  }
  int crow = bm * 128 + wr + (lane >> 4) * 4;
  int ccol0 = bn * 128 + wc + lrow;
#pragma unroll
  for (int m = 0; m < 4; ++m)
#pragma unroll
    for (int n = 0; n < 4; ++n) {
      int col = ccol0 + n * 16;
      float bv = bias[col];
#pragma unroll
      for (int r = 0; r < 4; ++r)
        C[(size_t)(crow + m * 16 + r) * GN + col] = acc[m][n][r] + bv;
    }
}

// ---------------- recurrence: 32 persistent blocks (16/direction), weights in VGPR/AGPRs ----------------
// Block b: dir = b>>4, chunk m = b&15 -> owns h elements [32m, 32m+32).
// Thread t: row_local = t>>2 (0..127), kseg = t&3 (128-elem K segment).
// Sync protocol (all cache-maintenance-free):
//   h data + flags move as RELAXED agent-scope atomics (sc1 bits -> bypass non-coherent
//   L1/XCD-L2, served by coherent LLC). Ordering via workgroup-scope fences which compile
//   to bare s_waitcnt (no buffer_inv / wbl2): producer drains h-store acks before flag
//   store; consumer orders poll-exit before h loads. Round-1's ACQUIRE-per-poll-iteration
//   emitted a full cache invalidate per spin iteration (~7us/step, 99% of kernel time).
__global__ __launch_bounds__(512, 2) void lstm_recur(const float* __restrict__ Whh_f,
                                                     const float* __restrict__ Whh_b,
                                                     const float* __restrict__ xp,
                                                     float* __restrict__ h_hist,
                                                     unsigned* __restrict__ flags) {
  int b = blockIdx.x;
  int dir = b >> 4;
  int m = b & 15;
  int tid = threadIdx.x;
  const float* Whh = dir ? Whh_b : Whh_f;
  int row_local = tid >> 2;
  int kseg = tid & 3;
  int R = ((row_local >> 5) << 9) + (m << 5) + (row_local & 31);  // gate*512 + m*32 + jj
  float w[128];
  {
    const float4* wsrc = (const float4*)(Whh + (size_t)R * HDIM + kseg * 128);
#pragma unroll
    for (int u = 0; u < 32; ++u) {
      float4 v = wsrc[u];
      w[4 * u] = v.x; w[4 * u + 1] = v.y; w[4 * u + 2] = v.z; w[4 * u + 3] = v.w;
    }
  }
  // padded h staging: value v stored at (v>>7)*132 + (v&127)  -> kseg bases on distinct banks
  __shared__ float h_lds[2][544];
  __shared__ float gates_lds[128];
  float c = 0.f;
  unsigned* myflags = flags + (size_t)dir * T_LEN * NCHUNK;
  float* h_dir = h_hist + (size_t)dir * T_LEN * HDIM;
  const float* xp_dir = xp + dir * H4;
  int pollpos = ((tid >> 7) * 132) + (tid & 127);
  int hbase_off = kseg * 132;

  for (int s = 0; s < T_LEN; ++s) {
    int pos = dir ? (T_LEN - 1 - s) : s;
    // prefetch x_proj for this step early (latency hides under poll + matvec)
    float xi = 0.f, xf_ = 0.f, xg = 0.f, xo = 0.f;
    if (tid < 32) {
      const float* xr = xp_dir + (size_t)pos * (2 * H4) + (m << 5) + tid;
      xi = xr[0]; xf_ = xr[512]; xg = xr[1024]; xo = xr[1536];
    }
    int buf = s & 1;
    if (s == 0) {
      h_lds[0][pollpos] = 0.f;
    } else {
      int prevpos = dir ? (pos + 1) : (pos - 1);
      // relaxed spin: plain sc1 load per iteration, no cache invalidates
      const unsigned* fp = myflags + (size_t)(s - 1) * NCHUNK + (tid >> 5);
      while (__hip_atomic_load(fp, __ATOMIC_RELAXED, __HIP_MEMORY_SCOPE_AGENT) != (unsigned)s) {}
      // compiler/issue barrier only (s_waitcnt, no cache ops)
      __builtin_amdgcn_fence(__ATOMIC_ACQUIRE, "workgroup");
      float hv = __hip_atomic_load(h_dir + (size_t)prevpos * HDIM + tid,
                                   __ATOMIC_RELAXED, __HIP_MEMORY_SCOPE_AGENT);
      h_lds[buf][pollpos] = hv;
    }
    __syncthreads();
    // matvec partial: 128 FMAs over this thread's K segment
    float part = 0.f;
    const float* hb = &h_lds[buf][hbase_off];
#pragma unroll
    for (int u = 0; u < 32; ++u) {
      float4 h4 = *(const float4*)(hb + u * 4);
      part = fmaf(w[4 * u], h4.x, part);
      part = fmaf(w[4 * u + 1], h4.y, part);
      part = fmaf(w[4 * u + 2], h4.z, part);
      part = fmaf(w[4 * u + 3], h4.w, part);
    }
    part += __shfl_xor(part, 1);
    part += __shfl_xor(part, 2);
    if (kseg == 0) gates_lds[row_local] = part;
    __syncthreads();
    if (tid < 64) {
      if (tid < 32) {
        float gi = gates_lds[tid] + xi;
        float gf = gates_lds[32 + tid] + xf_;
        float gg = gates_lds[64 + tid] + xg;
        float go = gates_lds[96 + tid] + xo;
        float iv = 1.f / (1.f + __expf(-gi));
        float fv = 1.f / (1.f + __expf(-gf));
        float gv = 1.f - 2.f / (1.f + __expf(2.f * gg));
        float ov = 1.f / (1.f + __expf(-go));
        c = fmaf(fv, c, iv * gv);
        float hv = ov * (1.f - 2.f / (1.f + __expf(2.f * c)));
        __hip_atomic_store(h_dir + (size_t)pos * HDIM + (m << 5) + tid, hv,
                           __ATOMIC_RELAXED, __HIP_MEMORY_SCOPE_AGENT);
      }
      // drain h-store acks (s_waitcnt vmcnt(0) only), then publish flag relaxed
      __builtin_amdgcn_fence(__ATOMIC_RELEASE, "workgroup");
      if (tid == 0) {
        __hip_atomic_store(myflags + (size_t)s * NCHUNK + m, (unsigned)(s + 1),
                           __ATOMIC_RELAXED, __HIP_MEMORY_SCOPE_AGENT);
      }
    }
  }
}

// ---------------- head: [h_f ; h_b] @ W_out.T + b_out, then log_softmax ----------------
__global__ __launch_bounds__(256) void head_ls(const float* __restrict__ h_hist,
                                               const float* __restrict__ W_out,
                                               const float* __restrict__ b_out,
                                               float* __restrict__ out) {
  int gw = (int)((blockIdx.x * 256 + threadIdx.x) >> 6);  // one wave per timestep
  int lane = threadIdx.x & 63;
  if (gw >= T_LEN) return;
  const float* hf = h_hist + (size_t)gw * HDIM;
  const float* hb = h_hist + (size_t)(T_LEN + gw) * HDIM;
  float p0 = 0.f, p1 = 0.f;
#pragma unroll
  for (int k = 0; k < 8; ++k) {
    int kk = lane + k * 64;
    float vf = hf[kk];
    float vb = hb[kk];
    p0 += vf * W_out[kk] + vb * W_out[512 + kk];
    p1 += vf * W_out[1024 + kk] + vb * W_out[1536 + kk];
  }
#pragma unroll
  for (int off = 32; off > 0; off >>= 1) {
    p0 += __shfl_down(p0, off);
    p1 += __shfl_down(p1, off);
  }
  if (lane == 0) {
    float z0 = p0 + b_out[0];
    float z1 = p1 + b_out[1];
    float mx = fmaxf(z0, z1);
    float lse = mx + logf(expf(z0 - mx) + expf(z1 - mx));
    out[(size_t)gw * 2] = z0 - lse;
    out[(size_t)gw * 2 + 1] = z1 - lse;
  }
}

extern "C" void kernel_launch(void* const* d_in, const int* in_sizes, int n_in,
                              void* d_out, int out_size, void* d_ws, size_t ws_size,
                              hipStream_t stream) {
  const int* idx = (const int*)d_in[0];
  const float* table = (const float*)d_in[1];
  const float* Wih_f = (const float*)d_in[2];
  const float* Whh_f = (const float*)d_in[3];
  const float* bih_f = (const float*)d_in[4];
  const float* bhh_f = (const float*)d_in[5];
  const float* Wih_b = (const float*)d_in[6];
  const float* Whh_b = (const float*)d_in[7];
  const float* bih_b = (const float*)d_in[8];
  const float* bhh_b = (const float*)d_in[9];
  const float* W_out = (const float*)d_in[10];
  const float* b_out = (const float*)d_in[11];
  float* out = (float*)d_out;
  char* ws = (char*)d_ws;

  // workspace layout (bytes)
  float* xp = (float*)(ws + 0);                               // [8192][4096] f32 = 128 MiB
  float* h_hist = (float*)(ws + 134217728ULL);                // [2][8192][512] f32 = 32 MiB
  unsigned* flags = (unsigned*)(ws + 167772160ULL);           // [2][8192][16] u32 = 2 MiB
  unsigned short* emb = (unsigned short*)(ws + 169869312ULL); // [8192][512] bf16 = 8 MiB
  unsigned short* wih = (unsigned short*)(ws + 178257920ULL); // [4096][512] bf16 = 4 MiB
  float* bias = (float*)(ws + 182452224ULL);                  // [4096] f32

  hipLaunchKernelGGL(prep_emb, dim3(T_LEN), dim3(256), 0, stream, idx, table, emb);
  hipLaunchKernelGGL(prep_w, dim3(8192), dim3(256), 0, stream,
                     Wih_f, Wih_b, bih_f, bhh_f, bih_b, bhh_b, wih, bias);
  hipLaunchKernelGGL(gemm_xp, dim3(2048), dim3(256), 0, stream, emb, wih, bias, xp);
  hipLaunchKernelGGL(lstm_recur, dim3(32), dim3(512), 0, stream, Whh_f, Whh_b, xp, h_hist, flags);
  hipLaunchKernelGGL(head_ls, dim3(2048), dim3(256), 0, stream, h_hist, W_out, b_out, out);
}

// Round 5
// 17207.887 us; speedup vs baseline: 3.4035x; 1.1622x over previous
//
#include <hip/hip_runtime.h>

#define T_LEN 8192
#define EDIM 512
#define HDIM 512
#define H4 2048
#define NCHUNK 16   // blocks per direction; each block owns 32 h-elements

typedef __attribute__((ext_vector_type(8))) short bf16x8;
typedef __attribute__((ext_vector_type(4))) float f32x4;
typedef __attribute__((ext_vector_type(2))) float f32x2;

__device__ __forceinline__ unsigned short f2bf(float x) {
  unsigned u = __float_as_uint(x);
  u += 0x7FFFu + ((u >> 16) & 1u);   // round-to-nearest-even
  return (unsigned short)(u >> 16);
}

// ---------------- prep: embedding gather + cast to bf16 ----------------
__global__ __launch_bounds__(256) void prep_emb(const int* __restrict__ idx,
                                                const float* __restrict__ table,
                                                unsigned short* __restrict__ emb) {
  int t = blockIdx.x;
  int k = threadIdx.x * 2;
  float2 v = *(const float2*)(table + (size_t)idx[t] * EDIM + k);
  ushort2 o;
  o.x = f2bf(v.x);
  o.y = f2bf(v.y);
  *(ushort2*)(emb + (size_t)t * EDIM + k) = o;
}

// ---------------- prep: Wih concat cast + bias sums ----------------
__global__ __launch_bounds__(256) void prep_w(const float* __restrict__ Wf,
                                              const float* __restrict__ Wb,
                                              const float* __restrict__ bif,
                                              const float* __restrict__ bhf,
                                              const float* __restrict__ bib,
                                              const float* __restrict__ bhb,
                                              unsigned short* __restrict__ WT,
                                              float* __restrict__ bias) {
  size_t gid = (size_t)blockIdx.x * 256 + threadIdx.x;  // 0 .. 4096*512
  float v = (gid < (size_t)H4 * EDIM) ? Wf[gid] : Wb[gid - (size_t)H4 * EDIM];
  WT[gid] = f2bf(v);
  if (gid < 2 * H4) {
    bias[gid] = (gid < H4) ? (bif[gid] + bhf[gid]) : (bib[gid - H4] + bhb[gid - H4]);
  }
}

// ---------------- x_proj GEMM: [8192,512]bf16 x [512,4096]bf16 -> f32 + bias ----------------
__global__ __launch_bounds__(256) void gemm_xp(const unsigned short* __restrict__ A,
                                               const unsigned short* __restrict__ BT,
                                               const float* __restrict__ bias,
                                               float* __restrict__ C) {
  __shared__ unsigned short As[128 * 32];
  __shared__ unsigned short Bs[128 * 32];
  const int GN = 2 * H4;  // 4096
  const int GK = EDIM;    // 512
  int bm = blockIdx.x >> 5;   // 0..63
  int bn = blockIdx.x & 31;   // 0..31
  int tid = threadIdx.x;
  int wave = tid >> 6, lane = tid & 63;
  int wr = (wave >> 1) * 64, wc = (wave & 1) * 64;
  int lrow = lane & 15, lk = (lane >> 4) * 8;
  f32x4 acc[4][4] = {};
  int sr = tid >> 1;
  int sc = (tid & 1) * 16;
  const size_t arow = (size_t)(bm * 128 + sr) * GK;
  const size_t brow = (size_t)(bn * 128 + sr) * GK;
  for (int k0 = 0; k0 < GK; k0 += 32) {
    __syncthreads();
    const uint4* sa = (const uint4*)(A + arow + k0 + sc);
    uint4 a0 = sa[0], a1 = sa[1];
    const uint4* sb = (const uint4*)(BT + brow + k0 + sc);
    uint4 b0 = sb[0], b1 = sb[1];
    uint4* da = (uint4*)&As[sr * 32 + sc]; da[0] = a0; da[1] = a1;
    uint4* db = (uint4*)&Bs[sr * 32 + sc]; db[0] = b0; db[1] = b1;
    __syncthreads();
    bf16x8 af[4], bfr[4];
#pragma unroll
    for (int m = 0; m < 4; ++m) af[m] = *(const bf16x8*)&As[(wr + m * 16 + lrow) * 32 + lk];
#pragma unroll
    for (int n = 0; n < 4; ++n) bfr[n] = *(const bf16x8*)&Bs[(wc + n * 16 + lrow) * 32 + lk];
#pragma unroll
    for (int m = 0; m < 4; ++m)
#pragma unroll
      for (int n = 0; n < 4; ++n)
        acc[m][n] = __builtin_amdgcn_mfma_f32_16x16x32_bf16(af[m], bfr[n], acc[m][n], 0, 0, 0);
  }
  int crow = bm * 128 + wr + (lane >> 4) * 4;
  int ccol0 = bn * 128 + wc + lrow;
#pragma unroll
  for (int m = 0; m < 4; ++m)
#pragma unroll
    for (int n = 0; n < 4; ++n) {
      int col = ccol0 + n * 16;
      float bv = bias[col];
#pragma unroll
      for (int r = 0; r < 4; ++r)
        C[(size_t)(crow + m * 16 + r) * GN + col] = acc[m][n][r] + bv;
    }
}

// ---------------- recurrence: 32 persistent blocks, self-announcing u64 h mailbox ----------------
// Block b: dir=b>>4, chunk m=b&15 owns h[32m..32m+32).
// Thread t: quad q=t>>2 -> gate g=q&3, output j=q>>2 (0..31); kseg=t&3 (128-elem K segment).
// Sync: h published as ONE u64 = (f32(h)<<32) | step_tag, relaxed agent-scope store (sc1 ->
// coherent LLC; naturally-aligned 8B store is single-copy atomic, so the tag travels with
// a FULL-PRECISION f32 payload: no fence, no separate flag, no store-ack drain). The
// consumer's poll IS the data load. Ring depth 4 (max inter-block lag = 1 step; slot s&3
// never collides with polled slot (s-1)&3). Tags 1..8192 != 0xAAAAAAAA poison.
// ROUND-4 LESSON: cross-lane __shfl under a divergent exec mask (inside if(is_head)) reads
// from INACTIVE source lanes -> undefined/zero on CDNA (identical absmax 0.0586 in rounds
// 3+4 regardless of payload dtype). All cross-lane ops now execute unconditionally with
// full exec; results are simply unused in non-head lanes.
__global__ __launch_bounds__(512, 2) void lstm_recur(const float* __restrict__ Whh_f,
                                                     const float* __restrict__ Whh_b,
                                                     const float* __restrict__ xp,
                                                     float* __restrict__ h_hist,
                                                     unsigned long long* __restrict__ mail) {
  int b = blockIdx.x;
  int dir = b >> 4;
  int m = b & 15;
  int tid = threadIdx.x;
  const float* Whh = dir ? Whh_b : Whh_f;
  int g = (tid >> 2) & 3;
  int j = tid >> 4;
  int kseg = tid & 3;
  int R = (g << 9) + (m << 5) + j;  // gate*512 + m*32 + j
  f32x2 w2[64];
  {
    const float4* wsrc = (const float4*)(Whh + (size_t)R * HDIM + kseg * 128);
#pragma unroll
    for (int u = 0; u < 32; ++u) {
      float4 v = wsrc[u];
      w2[2 * u] = f32x2{v.x, v.y};
      w2[2 * u + 1] = f32x2{v.z, v.w};
    }
  }
  // padded h staging: value v at (v>>7)*132 + (v&127) -> kseg bases on distinct banks
  __shared__ float h_lds[2][544];
  float c = 0.f;
  unsigned long long* mail_dir = mail + (size_t)dir * 4 * HDIM;
  float* h_dir = h_hist + (size_t)dir * T_LEN * HDIM;
  const float* xp_dir = xp + dir * H4;
  const int pollpos = ((tid >> 7) * 132) + (tid & 127);
  const int hbase_off = kseg * 132;
  const int lane = tid & 63;
  const bool is_head = (tid & 15) == 0;  // owns output j = tid>>4

  for (int s = 0; s < T_LEN; ++s) {
    int pos = dir ? (T_LEN - 1 - s) : s;
    // prefetch x_proj for this step (hides under poll + matvec)
    float xi = 0.f, xf_ = 0.f, xg = 0.f, xo = 0.f;
    if (is_head) {
      const float* xr = xp_dir + (size_t)pos * (2 * H4) + (m << 5) + j;
      xi = xr[0]; xf_ = xr[512]; xg = xr[1024]; xo = xr[1536];
    }
    int buf = s & 1;
    if (s == 0) {
      h_lds[0][pollpos] = 0.f;
    } else {
      const unsigned long long* wp = mail_dir + (size_t)((s - 1) & 3) * HDIM + tid;
      unsigned tag = (unsigned)s;
      unsigned long long v;
      for (;;) {
        unsigned long long v0 = __hip_atomic_load(wp, __ATOMIC_RELAXED, __HIP_MEMORY_SCOPE_AGENT);
        unsigned long long v1 = __hip_atomic_load(wp, __ATOMIC_RELAXED, __HIP_MEMORY_SCOPE_AGENT);
        if ((unsigned)v0 == tag) { v = v0; break; }
        if ((unsigned)v1 == tag) { v = v1; break; }
      }
      h_lds[buf][pollpos] = __uint_as_float((unsigned)(v >> 32));
    }
    __syncthreads();
    // matvec partial: 128 MACs over this thread's K segment (f32x2 for v_pk_fma_f32)
    f32x2 a0 = {0.f, 0.f}, a1 = {0.f, 0.f};
    const float* hb = &h_lds[buf][hbase_off];
#pragma unroll
    for (int u = 0; u < 32; ++u) {
      float4 h4 = *(const float4*)(hb + u * 4);
      a0 = __builtin_elementwise_fma(w2[2 * u], f32x2{h4.x, h4.y}, a0);
      a1 = __builtin_elementwise_fma(w2[2 * u + 1], f32x2{h4.z, h4.w}, a1);
    }
    float part = a0.x + a0.y + a1.x + a1.y;
    // reduce over kseg (lanes 4q+k): quad-local butterfly — full exec
    part += __shfl_xor(part, 1);
    part += __shfl_xor(part, 2);
    // gate collection: UNCONDITIONAL cross-lane reads (all 64 lanes active -> sources
    // guaranteed active); head lane (lane&15)==0 sees quads +1,+2,+3 = gates f,g,o
    float pf = __shfl(part, lane + 4);
    float pg = __shfl(part, lane + 8);
    float po = __shfl(part, lane + 12);
    if (is_head) {
      float gi = part + xi;
      float gf = pf + xf_;
      float gg = pg + xg;
      float go = po + xo;
      float iv = 1.f / (1.f + __expf(-gi));
      float fv = 1.f / (1.f + __expf(-gf));
      float gv = 1.f - 2.f / (1.f + __expf(2.f * gg));
      float ov = 1.f / (1.f + __expf(-go));
      c = fmaf(fv, c, iv * gv);
      float hv = ov * (1.f - 2.f / (1.f + __expf(2.f * c)));
      // f32 history for the head (off critical path; kernel-boundary visibility)
      h_dir[(size_t)pos * HDIM + (m << 5) + j] = hv;
      // publish: f32 payload + step tag in one u64, fire-and-forget
      unsigned long long pkt =
          ((unsigned long long)__float_as_uint(hv) << 32) | (unsigned long long)(unsigned)(s + 1);
      __hip_atomic_store(mail_dir + (size_t)(s & 3) * HDIM + (m << 5) + j, pkt,
                         __ATOMIC_RELAXED, __HIP_MEMORY_SCOPE_AGENT);
    }
  }
}

// ---------------- head: [h_f ; h_b] @ W_out.T + b_out, then log_softmax ----------------
__global__ __launch_bounds__(256) void head_ls(const float* __restrict__ h_hist,
                                               const float* __restrict__ W_out,
                                               const float* __restrict__ b_out,
                                               float* __restrict__ out) {
  int gw = (int)((blockIdx.x * 256 + threadIdx.x) >> 6);  // one wave per timestep
  int lane = threadIdx.x & 63;
  if (gw >= T_LEN) return;
  const float* hf = h_hist + (size_t)gw * HDIM;
  const float* hb = h_hist + (size_t)(T_LEN + gw) * HDIM;
  float p0 = 0.f, p1 = 0.f;
#pragma unroll
  for (int k = 0; k < 8; ++k) {
    int kk = lane + k * 64;
    float vf = hf[kk];
    float vb = hb[kk];
    p0 += vf * W_out[kk] + vb * W_out[512 + kk];
    p1 += vf * W_out[1024 + kk] + vb * W_out[1536 + kk];
  }
#pragma unroll
  for (int off = 32; off > 0; off >>= 1) {
    p0 += __shfl_down(p0, off);
    p1 += __shfl_down(p1, off);
  }
  if (lane == 0) {
    float z0 = p0 + b_out[0];
    float z1 = p1 + b_out[1];
    float mx = fmaxf(z0, z1);
    float lse = mx + logf(expf(z0 - mx) + expf(z1 - mx));
    out[(size_t)gw * 2] = z0 - lse;
    out[(size_t)gw * 2 + 1] = z1 - lse;
  }
}

extern "C" void kernel_launch(void* const* d_in, const int* in_sizes, int n_in,
                              void* d_out, int out_size, void* d_ws, size_t ws_size,
                              hipStream_t stream) {
  const int* idx = (const int*)d_in[0];
  const float* table = (const float*)d_in[1];
  const float* Wih_f = (const float*)d_in[2];
  const float* Whh_f = (const float*)d_in[3];
  const float* bih_f = (const float*)d_in[4];
  const float* bhh_f = (const float*)d_in[5];
  const float* Wih_b = (const float*)d_in[6];
  const float* Whh_b = (const float*)d_in[7];
  const float* bih_b = (const float*)d_in[8];
  const float* bhh_b = (const float*)d_in[9];
  const float* W_out = (const float*)d_in[10];
  const float* b_out = (const float*)d_in[11];
  float* out = (float*)d_out;
  char* ws = (char*)d_ws;

  // workspace layout (bytes)
  float* xp = (float*)(ws + 0);                                    // [8192][4096] f32 = 128 MiB
  float* h_hist = (float*)(ws + 134217728ULL);                     // [2][8192][512] f32 = 32 MiB
  unsigned long long* mail = (unsigned long long*)(ws + 167772160ULL); // [2][4][512] u64 = 32 KiB
  unsigned short* emb = (unsigned short*)(ws + 167804928ULL);      // [8192][512] bf16 = 8 MiB
  unsigned short* wih = (unsigned short*)(ws + 176193536ULL);      // [4096][512] bf16 = 4 MiB
  float* bias = (float*)(ws + 180387840ULL);                       // [4096] f32

  hipLaunchKernelGGL(prep_emb, dim3(T_LEN), dim3(256), 0, stream, idx, table, emb);
  hipLaunchKernelGGL(prep_w, dim3(8192), dim3(256), 0, stream,
                     Wih_f, Wih_b, bih_f, bhh_f, bih_b, bhh_b, wih, bias);
  hipLaunchKernelGGL(gemm_xp, dim3(2048), dim3(256), 0, stream, emb, wih, bias, xp);
  hipLaunchKernelGGL(lstm_recur, dim3(32), dim3(512), 0, stream, Whh_f, Whh_b, xp, h_hist, mail);
  hipLaunchKernelGGL(head_ls, dim3(2048), dim3(256), 0, stream, h_hist, W_out, b_out, out);
}

// Round 7
// 13593.568 us; speedup vs baseline: 4.3085x; 1.2659x over previous
//
#include <hip/hip_runtime.h>

#define T_LEN 8192
#define EDIM 512
#define HDIM 512
#define H4 2048
#define NCHUNK 32   // blocks per direction; each block owns 16 h-elements

typedef __attribute__((ext_vector_type(8))) short bf16x8;
typedef __attribute__((ext_vector_type(4))) float f32x4;
typedef __attribute__((ext_vector_type(2))) float f32x2;

__device__ __forceinline__ unsigned short f2bf(float x) {
  unsigned u = __float_as_uint(x);
  u += 0x7FFFu + ((u >> 16) & 1u);   // round-to-nearest-even
  return (unsigned short)(u >> 16);
}

// ---------------- prep: embedding gather + cast to bf16 ----------------
__global__ __launch_bounds__(256) void prep_emb(const int* __restrict__ idx,
                                                const float* __restrict__ table,
                                                unsigned short* __restrict__ emb) {
  int t = blockIdx.x;
  int k = threadIdx.x * 2;
  float2 v = *(const float2*)(table + (size_t)idx[t] * EDIM + k);
  ushort2 o;
  o.x = f2bf(v.x);
  o.y = f2bf(v.y);
  *(ushort2*)(emb + (size_t)t * EDIM + k) = o;
}

// ---------------- prep: Wih concat cast + bias sums ----------------
__global__ __launch_bounds__(256) void prep_w(const float* __restrict__ Wf,
                                              const float* __restrict__ Wb,
                                              const float* __restrict__ bif,
                                              const float* __restrict__ bhf,
                                              const float* __restrict__ bib,
                                              const float* __restrict__ bhb,
                                              unsigned short* __restrict__ WT,
                                              float* __restrict__ bias) {
  size_t gid = (size_t)blockIdx.x * 256 + threadIdx.x;  // 0 .. 4096*512
  float v = (gid < (size_t)H4 * EDIM) ? Wf[gid] : Wb[gid - (size_t)H4 * EDIM];
  WT[gid] = f2bf(v);
  if (gid < 2 * H4) {
    bias[gid] = (gid < H4) ? (bif[gid] + bhf[gid]) : (bib[gid - H4] + bhb[gid - H4]);
  }
}

// ---------------- x_proj GEMM: [8192,512]bf16 x [512,4096]bf16 -> f32 + bias ----------------
__global__ __launch_bounds__(256) void gemm_xp(const unsigned short* __restrict__ A,
                                               const unsigned short* __restrict__ BT,
                                               const float* __restrict__ bias,
                                               float* __restrict__ C) {
  __shared__ unsigned short As[128 * 32];
  __shared__ unsigned short Bs[128 * 32];
  const int GN = 2 * H4;  // 4096
  const int GK = EDIM;    // 512
  int bm = blockIdx.x >> 5;   // 0..63
  int bn = blockIdx.x & 31;   // 0..31
  int tid = threadIdx.x;
  int wave = tid >> 6, lane = tid & 63;
  int wr = (wave >> 1) * 64, wc = (wave & 1) * 64;
  int lrow = lane & 15, lk = (lane >> 4) * 8;
  f32x4 acc[4][4] = {};
  int sr = tid >> 1;
  int sc = (tid & 1) * 16;
  const size_t arow = (size_t)(bm * 128 + sr) * GK;
  const size_t brow = (size_t)(bn * 128 + sr) * GK;
  for (int k0 = 0; k0 < GK; k0 += 32) {
    __syncthreads();
    const uint4* sa = (const uint4*)(A + arow + k0 + sc);
    uint4 a0 = sa[0], a1 = sa[1];
    const uint4* sb = (const uint4*)(BT + brow + k0 + sc);
    uint4 b0 = sb[0], b1 = sb[1];
    uint4* da = (uint4*)&As[sr * 32 + sc]; da[0] = a0; da[1] = a1;
    uint4* db = (uint4*)&Bs[sr * 32 + sc]; db[0] = b0; db[1] = b1;
    __syncthreads();
    bf16x8 af[4], bfr[4];
#pragma unroll
    for (int m = 0; m < 4; ++m) af[m] = *(const bf16x8*)&As[(wr + m * 16 + lrow) * 32 + lk];
#pragma unroll
    for (int n = 0; n < 4; ++n) bfr[n] = *(const bf16x8*)&Bs[(wc + n * 16 + lrow) * 32 + lk];
#pragma unroll
    for (int m = 0; m < 4; ++m)
#pragma unroll
      for (int n = 0; n < 4; ++n)
        acc[m][n] = __builtin_amdgcn_mfma_f32_16x16x32_bf16(af[m], bfr[n], acc[m][n], 0, 0, 0);
  }
  int crow = bm * 128 + wr + (lane >> 4) * 4;
  int ccol0 = bn * 128 + wc + lrow;
#pragma unroll
  for (int m = 0; m < 4; ++m)
#pragma unroll
    for (int n = 0; n < 4; ++n) {
      int col = ccol0 + n * 16;
      float bv = bias[col];
#pragma unroll
      for (int r = 0; r < 4; ++r)
        C[(size_t)(crow + m * 16 + r) * GN + col] = acc[m][n][r] + bv;
    }
}

// ---------------- recurrence: 64 persistent blocks (32/dir), u64 self-announcing mailbox ----------------
// Block b: dir=b>>5, chunk m=b&31 owns h[16m..16m+16).  256 threads:
// tid = j*16 + g*4 + kseg  (j=output 0..15, g=gate i/f/g/o, kseg=128-elem K segment).
// Per step: thread polls TWO mailbox words (tid, tid+256), stages to LDS, one barrier,
// 128 f32 MACs, quad butterfly over kseg, per-lane gate activation (branchless tanh via
// 2*sig(2x)-1), unconditional shfl collect (round-4 lesson: never shfl under divergent
// exec), head lane updates c and publishes (f32 h + step tag in ONE u64, relaxed agent
// store -> tag travels with payload; no fences anywhere in the loop).
// vs round 5: 256-thread blocks halve per-CU VALU issue + LDS traffic + barrier width
// (4 waves, 1/SIMD), and the producer tail is shortened by pre-collect activations.
// Deadlock audit: 64 blocks co-resident on 256 CUs; inter-block lag <= 1 step -> depth-4
// ring slots never collide; poison 0xAAAAAAAA not in tag range 1..8192.
__global__ __launch_bounds__(256, 1) void lstm_recur(const float* __restrict__ Whh_f,
                                                     const float* __restrict__ Whh_b,
                                                     const float* __restrict__ xp,
                                                     float* __restrict__ h_hist,
                                                     unsigned long long* __restrict__ mail) {
  int b = blockIdx.x;
  int dir = b >> 5;
  int m = b & 31;
  int tid = threadIdx.x;
  const float* Whh = dir ? Whh_b : Whh_f;
  int g = (tid >> 2) & 3;
  int j = tid >> 4;
  int kseg = tid & 3;
  int R = (g << 9) + (m << 4) + j;  // gate*512 + m*16 + j
  f32x2 w2[64];
  {
    const float4* wsrc = (const float4*)(Whh + (size_t)R * HDIM + kseg * 128);
#pragma unroll
    for (int u = 0; u < 32; ++u) {
      float4 v = wsrc[u];
      w2[2 * u] = f32x2{v.x, v.y};
      w2[2 * u + 1] = f32x2{v.z, v.w};
    }
  }
  // padded h staging: value v at (v>>7)*132 + (v&127) -> kseg bases on distinct banks
  __shared__ float h_lds[2][544];
  float c = 0.f;
  unsigned long long* mail_dir = mail + (size_t)dir * 4 * HDIM;
  float* h_dir = h_hist + (size_t)dir * T_LEN * HDIM;
  const float* xp_dir = xp + dir * H4;
  const int p0 = ((tid >> 7) * 132) + (tid & 127);        // stage slot for value tid
  const int p1 = p0 + 2 * 132;                            // stage slot for value tid+256
  const int hbase_off = kseg * 132;
  const int lane = tid & 63;
  const bool is_head = (tid & 15) == 0;
  const float tmul = (g == 2) ? 2.f : 1.f;                // tanh gate: act = 2*sig(2x)-1

  for (int s = 0; s < T_LEN; ++s) {
    int pos = dir ? (T_LEN - 1 - s) : s;
    // per-lane x_proj value for (gate g, output j) — issued early, consumed post-matvec
    float xq = xp_dir[(size_t)pos * (2 * H4) + (g << 9) + (m << 4) + j];
    int buf = s & 1;
    if (s == 0) {
      h_lds[0][p0] = 0.f;
      h_lds[0][p1] = 0.f;
    } else {
      const unsigned long long* wp0 = mail_dir + (size_t)((s - 1) & 3) * HDIM + tid;
      const unsigned long long* wp1 = wp0 + 256;
      unsigned tag = (unsigned)s;
      unsigned long long v0, v1;
      for (;;) {
        v0 = __hip_atomic_load(wp0, __ATOMIC_RELAXED, __HIP_MEMORY_SCOPE_AGENT);
        v1 = __hip_atomic_load(wp1, __ATOMIC_RELAXED, __HIP_MEMORY_SCOPE_AGENT);
        if ((unsigned)v0 == tag && (unsigned)v1 == tag) break;
      }
      h_lds[buf][p0] = __uint_as_float((unsigned)(v0 >> 32));
      h_lds[buf][p1] = __uint_as_float((unsigned)(v1 >> 32));
    }
    __syncthreads();
    // matvec partial: 128 MACs over this thread's K segment
    f32x2 a0 = {0.f, 0.f}, a1 = {0.f, 0.f};
    const float* hb = &h_lds[buf][hbase_off];
#pragma unroll
    for (int u = 0; u < 32; ++u) {
      float4 h4 = *(const float4*)(hb + u * 4);
      a0 = __builtin_elementwise_fma(w2[2 * u], f32x2{h4.x, h4.y}, a0);
      a1 = __builtin_elementwise_fma(w2[2 * u + 1], f32x2{h4.z, h4.w}, a1);
    }
    float part = a0.x + a0.y + a1.x + a1.y;
    // reduce over kseg (4-lane butterfly) — full exec
    part += __shfl_xor(part, 1);
    part += __shfl_xor(part, 2);
    // per-lane gate activation BEFORE collect (shortens head's serial tail)
    float aa = (part + xq) * tmul;
    float t = 1.f / (1.f + __expf(-aa));
    float act = (g == 2) ? (2.f * t - 1.f) : t;
    // unconditional cross-lane collect (sources guaranteed active)
    float fv = __shfl(act, lane + 4);
    float gv = __shfl(act, lane + 8);
    float ov = __shfl(act, lane + 12);
    if (is_head) {
      float iv = act;
      c = fmaf(fv, c, iv * gv);
      float hv = ov * (1.f - 2.f / (1.f + __expf(2.f * c)));
      // publish FIRST: f32 payload + step tag in one u64, fire-and-forget
      unsigned long long pkt =
          ((unsigned long long)__float_as_uint(hv) << 32) | (unsigned long long)(unsigned)(s + 1);
      __hip_atomic_store(mail_dir + (size_t)(s & 3) * HDIM + (m << 4) + j, pkt,
                         __ATOMIC_RELAXED, __HIP_MEMORY_SCOPE_AGENT);
      // f32 history for the head kernel (off critical path)
      h_dir[(size_t)pos * HDIM + (m << 4) + j] = hv;
    }
  }
}

// ---------------- head: [h_f ; h_b] @ W_out.T + b_out, then log_softmax ----------------
__global__ __launch_bounds__(256) void head_ls(const float* __restrict__ h_hist,
                                               const float* __restrict__ W_out,
                                               const float* __restrict__ b_out,
                                               float* __restrict__ out) {
  int gw = (int)((blockIdx.x * 256 + threadIdx.x) >> 6);  // one wave per timestep
  int lane = threadIdx.x & 63;
  if (gw >= T_LEN) return;
  const float* hf = h_hist + (size_t)gw * HDIM;
  const float* hb = h_hist + (size_t)(T_LEN + gw) * HDIM;
  float p0 = 0.f, p1 = 0.f;
#pragma unroll
  for (int k = 0; k < 8; ++k) {
    int kk = lane + k * 64;
    float vf = hf[kk];
    float vb = hb[kk];
    p0 += vf * W_out[kk] + vb * W_out[512 + kk];
    p1 += vf * W_out[1024 + kk] + vb * W_out[1536 + kk];
  }
#pragma unroll
  for (int off = 32; off > 0; off >>= 1) {
    p0 += __shfl_down(p0, off);
    p1 += __shfl_down(p1, off);
  }
  if (lane == 0) {
    float z0 = p0 + b_out[0];
    float z1 = p1 + b_out[1];
    float mx = fmaxf(z0, z1);
    float lse = mx + logf(expf(z0 - mx) + expf(z1 - mx));
    out[(size_t)gw * 2] = z0 - lse;
    out[(size_t)gw * 2 + 1] = z1 - lse;
  }
}

extern "C" void kernel_launch(void* const* d_in, const int* in_sizes, int n_in,
                              void* d_out, int out_size, void* d_ws, size_t ws_size,
                              hipStream_t stream) {
  const int* idx = (const int*)d_in[0];
  const float* table = (const float*)d_in[1];
  const float* Wih_f = (const float*)d_in[2];
  const float* Whh_f = (const float*)d_in[3];
  const float* bih_f = (const float*)d_in[4];
  const float* bhh_f = (const float*)d_in[5];
  const float* Wih_b = (const float*)d_in[6];
  const float* Whh_b = (const float*)d_in[7];
  const float* bih_b = (const float*)d_in[8];
  const float* bhh_b = (const float*)d_in[9];
  const float* W_out = (const float*)d_in[10];
  const float* b_out = (const float*)d_in[11];
  float* out = (float*)d_out;
  char* ws = (char*)d_ws;

  // workspace layout (bytes)
  float* xp = (float*)(ws + 0);                                    // [8192][4096] f32 = 128 MiB
  float* h_hist = (float*)(ws + 134217728ULL);                     // [2][8192][512] f32 = 32 MiB
  unsigned long long* mail = (unsigned long long*)(ws + 167772160ULL); // [2][4][512] u64 = 32 KiB
  unsigned short* emb = (unsigned short*)(ws + 167804928ULL);      // [8192][512] bf16 = 8 MiB
  unsigned short* wih = (unsigned short*)(ws + 176193536ULL);      // [4096][512] bf16 = 4 MiB
  float* bias = (float*)(ws + 180387840ULL);                       // [4096] f32

  hipLaunchKernelGGL(prep_emb, dim3(T_LEN), dim3(256), 0, stream, idx, table, emb);
  hipLaunchKernelGGL(prep_w, dim3(8192), dim3(256), 0, stream,
                     Wih_f, Wih_b, bih_f, bhh_f, bih_b, bhh_b, wih, bias);
  hipLaunchKernelGGL(gemm_xp, dim3(2048), dim3(256), 0, stream, emb, wih, bias, xp);
  hipLaunchKernelGGL(lstm_recur, dim3(64), dim3(256), 0, stream, Whh_f, Whh_b, xp, h_hist, mail);
  hipLaunchKernelGGL(head_ls, dim3(2048), dim3(256), 0, stream, h_hist, W_out, b_out, out);
}